// Round 8
// baseline (153.641 us; speedup 1.0000x reference)
//
#include <hip/hip_runtime.h>
#include <math.h>

#define NNODES 100000
#define NEDGES 100000
#define NNZV   1600000
#define KDIM   64
#define LAMBDA 0.1f

// S1 (edge-bucketed) geometry: 64 edges per bucket.
#define NB1   1563       // ceil(100000/64)
#define BSH1  6
#define BM1   63
#define CAP1  1536       // mean 1024, sd~32 -> +16 sigma
// S2 (node-bucketed) geometry: 128 nodes per bucket.
#define NB2   782        // ceil(100000/128)
#define BSH2  7
#define BM2   127
#define CAP2  3072       // mean 2048, sd~45 -> +22 sigma

#define A0B   256        // chunks (CHUNK elements each)
#define A0T   1024
#define CHUNK 6250       // NNZV / A0B exactly
#define GMB   256        // blocks for fused yzg kernel

// ---- workspace layout (bytes), 256-aligned ----
#define OFF_DV      0           // N f32
#define OFF_G       400128      // 4096 f32 (memset, atomic accum)
#define OFF_PART    416512      // NB1 f32
#define OFF_ZN      422912      // GMB f32
#define OFF_CNTB    423936      // NB1 u32
#define OFF_CNTB2   430336      // NB2 u32
#define OFF_HIST    433664      // A0B*NB1 u32
#define OFF_HIST2   2034176     // A0B*NB2 u32
#define OFF_BASE1   2834944     // A0B*NB1 u32
#define OFF_BASE2   4435456     // A0B*NB2 u32
#define OFF_S1      5236224     // NB1*CAP1 u32 (node | elocal<<17)
#define OFF_S2      14839296    // NB2*CAP2 u32 ((wbits&~0x7F) | nlocal)
#define OFF_YQ      24448512    // N*K fp8
// total 30848512

#if defined(__has_builtin)
#if __has_builtin(__builtin_amdgcn_cvt_f32_fp8)
#define HAS_CVT_FP8 1
#endif
#if __has_builtin(__builtin_amdgcn_cvt_pk_fp8_f32)
#define HAS_PK_FP8 1
#endif
#endif

__device__ __forceinline__ int load_node(const unsigned* idx, int i, bool i64) {
    return (int)(i64 ? idx[2 * i] : idx[i]);
}
__device__ __forceinline__ int load_edge(const unsigned* idx, int i, bool i64) {
    return (int)(i64 ? idx[2 * (NNZV + i)] : idx[NNZV + i]);
}

// f32 -> fp8 e4m3fn, RNE (fallback when no HW packed cvt).
__device__ __forceinline__ unsigned char enc_fp8(float x) {
    unsigned u = __float_as_uint(x);
    unsigned s = (u >> 31) << 7;
    unsigned mag = u & 0x7FFFFFFFu;
    if (mag >= 0x43E00000u) return (unsigned char)(s | 0x7Eu);
    if (mag < 0x3C800000u) {
        float a = __uint_as_float(mag);
        int m = (int)rintf(a * 512.0f);
        if (m >= 8) return (unsigned char)(s | 0x08u);
        return (unsigned char)(s | (unsigned)m);
    }
    unsigned lsb = (mag >> 20) & 1u;
    mag += 0x0007FFFFu + lsb;
    unsigned e = (mag >> 23) - 120u;
    return (unsigned char)(s | (e << 3) | ((mag >> 20) & 7u));
}

__device__ __forceinline__ unsigned pack_fp8x4(float y0, float y1, float y2, float y3) {
#ifdef HAS_PK_FP8
    int q = 0;
    q = __builtin_amdgcn_cvt_pk_fp8_f32(y0, y1, q, false);
    q = __builtin_amdgcn_cvt_pk_fp8_f32(y2, y3, q, true);
    return (unsigned)q;
#else
    return (unsigned)enc_fp8(y0) | ((unsigned)enc_fp8(y1) << 8) |
           ((unsigned)enc_fp8(y2) << 16) | ((unsigned)enc_fp8(y3) << 24);
#endif
}

template <int SEL>
__device__ __forceinline__ float dec_fp8(unsigned v) {
#ifdef HAS_CVT_FP8
    return __builtin_amdgcn_cvt_f32_fp8(v, SEL);
#else
    unsigned b = (v >> (8 * SEL)) & 0xFFu;
    unsigned e = (b >> 3) & 15u, m = b & 7u;
    float f = e ? __uint_as_float(((e + 120u) << 23) | (m << 20))
                : (float)m * 0.001953125f;
    return (b & 128u) ? -f : f;
#endif
}

// A0: histogram. Grid 2*A0B: which = blockIdx>>8 (0: edge keys/NB1, 1: node keys/NB2).
__global__ __launch_bounds__(A0T) void binh_kernel(const unsigned* __restrict__ idx,
                                                   unsigned* __restrict__ hist,
                                                   unsigned* __restrict__ hist2) {
    __shared__ unsigned h[NB1];
    __shared__ unsigned fred[16];
    int which = blockIdx.x >> 8, chunk = blockIdx.x & (A0B - 1);
    int nb = which ? NB2 : NB1;
    int t = threadIdx.x, wave = t >> 6, lane = t & 63;
    unsigned hv = idx[2 * t + 1];
#pragma unroll
    for (int off = 32; off; off >>= 1) hv |= __shfl_xor(hv, off);
    if (lane == 0) fred[wave] = hv;
    for (int j = t; j < nb; j += A0T) h[j] = 0u;
    __syncthreads();
    unsigned o = 0;
#pragma unroll
    for (int k = 0; k < 16; ++k) o |= fred[k];
    bool i64 = (o == 0u);
    int base = chunk * CHUNK;
    if (which == 0) {
        for (int i = base + t; i < base + CHUNK; i += A0T)
            atomicAdd(&h[load_edge(idx, i, i64) >> BSH1], 1u);
    } else {
        for (int i = base + t; i < base + CHUNK; i += A0T)
            atomicAdd(&h[load_node(idx, i, i64) >> BSH2], 1u);
    }
    __syncthreads();
    unsigned* H = which ? hist2 : hist;
    for (int j = t; j < nb; j += A0T) H[chunk * nb + j] = h[j];
}

// A1: per-bucket column scan -> absolute per-(chunk,bucket) bases; totals.
// Grid 11: blocks 0-6 handle S1 (NB1), 7-10 handle S2 (NB2).
__global__ void bscan_kernel(const unsigned* __restrict__ hist,
                             const unsigned* __restrict__ hist2,
                             unsigned* __restrict__ base1,
                             unsigned* __restrict__ base2,
                             unsigned* __restrict__ cntb,
                             unsigned* __restrict__ cntb2) {
    int which = (blockIdx.x >= 7);
    int b = (which ? (int)blockIdx.x - 7 : (int)blockIdx.x) * 256 + threadIdx.x;
    int nb = which ? NB2 : NB1;
    int cap = which ? CAP2 : CAP1;
    if (b >= nb) return;
    const unsigned* h = which ? hist2 : hist;
    unsigned* ba = which ? base2 : base1;
    unsigned run = 0;
    for (int blk = 0; blk < A0B; ++blk) {
        unsigned v = h[blk * nb + b];
        ba[blk * nb + b] = (unsigned)b * cap + run;
        run += v;
    }
    (which ? cntb2 : cntb)[b] = run;
}

// A2: LDS-staged multisplit scatter. Grid 2*A0B: which selects S1/S2.
__global__ __launch_bounds__(A0T) void bscat_kernel(const unsigned* __restrict__ idx,
                                                    const float* __restrict__ w,
                                                    const unsigned* __restrict__ hist,
                                                    const unsigned* __restrict__ hist2,
                                                    const unsigned* __restrict__ base1,
                                                    const unsigned* __restrict__ base2,
                                                    unsigned* __restrict__ S1,
                                                    unsigned* __restrict__ S2) {
    __shared__ unsigned stage[CHUNK];
    __shared__ unsigned cur[NB1];
    __shared__ unsigned wsum[16], fred[16];
    __shared__ unsigned carry_s, ctot;
    int which = blockIdx.x >> 8, chunk = blockIdx.x & (A0B - 1);
    int nb = which ? NB2 : NB1;
    int t = threadIdx.x, wave = t >> 6, lane = t & 63;

    unsigned hv = idx[2 * t + 1];
#pragma unroll
    for (int off = 32; off; off >>= 1) hv |= __shfl_xor(hv, off);
    if (lane == 0) fred[wave] = hv;
    if (t == 0) carry_s = 0;

    const unsigned* H = which ? hist2 : hist;
    const unsigned* B = which ? base2 : base1;
    unsigned* S = which ? S2 : S1;
    __syncthreads();

    // exclusive scan over nb counts (loop-carried, <=2 passes)
    for (int b0 = 0; b0 < nb; b0 += A0T) {
        int i = b0 + t;
        unsigned v = (i < nb) ? H[chunk * nb + i] : 0u;
        unsigned x = v;
#pragma unroll
        for (int off = 1; off < 64; off <<= 1) {
            unsigned y = __shfl_up(x, off);
            if (lane >= off) x += y;
        }
        if (lane == 63) wsum[wave] = x;
        __syncthreads();
        if (t < 16) {
            unsigned a = wsum[t], y = a;
#pragma unroll
            for (int off = 1; off < 16; off <<= 1) {
                unsigned z = __shfl_up(y, off);
                if (t >= off) y += z;
            }
            wsum[t] = y - a;
            if (t == 15) ctot = y;
        }
        __syncthreads();
        if (i < nb) cur[i] = carry_s + wsum[wave] + x - v;
        __syncthreads();
        if (t == 0) carry_s += ctot;
        __syncthreads();
    }
    unsigned o = 0;
#pragma unroll
    for (int k = 0; k < 16; ++k) o |= fred[k];
    bool i64 = (o == 0u);

    int base = chunk * CHUNK;
    if (which == 0) {
        for (int i = base + t; i < base + CHUNK; i += A0T) {
            int node = load_node(idx, i, i64);
            int edge = load_edge(idx, i, i64);
            unsigned p = atomicAdd(&cur[(unsigned)edge >> BSH1], 1u);
            stage[p] = (unsigned)node | ((unsigned)(edge & BM1) << 17);
        }
    } else {
        for (int i = base + t; i < base + CHUNK; i += A0T) {
            int node = load_node(idx, i, i64);
            int edge = load_edge(idx, i, i64);
            unsigned wb = __float_as_uint(w[edge]) & 0xFFFFFF80u;
            unsigned p = atomicAdd(&cur[(unsigned)node >> BSH2], 1u);
            stage[p] = wb | (unsigned)(node & BM2);
        }
    }
    __syncthreads();

    // coalesced per-bucket copy-out: 4 lanes/bucket (S1, runs~4), 8 (S2, runs~8)
    int lshift = which ? 3 : 2;
    int lpb = 1 << lshift;
    int bpw = 64 >> lshift;
    int li = lane & (lpb - 1);
    for (int bb = wave * bpw + (lane >> lshift); bb < nb; bb += 16 * bpw) {
        unsigned c = H[chunk * nb + bb];
        unsigned st = cur[bb] - c;
        unsigned g = B[chunk * nb + bb];
        for (unsigned m = li; m < c; m += lpb) S[g + m] = stage[st + m];
    }
}

// Dv build: per node-bucket LDS f32 accumulation; w pre-packed in S2 values.
__global__ __launch_bounds__(256) void dvb_kernel(const unsigned* __restrict__ S2,
                                                  const unsigned* __restrict__ cntb2,
                                                  float* __restrict__ Dv) {
    __shared__ float acc[128];
    int t = threadIdx.x, b = blockIdx.x;
    if (t < 128) acc[t] = 0.0f;
    __syncthreads();
    unsigned cnt = cntb2[b];
    const unsigned* src = S2 + (size_t)b * CAP2;
    for (unsigned i = t; i < cnt; i += 256) {
        unsigned v = src[i];
        atomicAdd(&acc[v & (unsigned)BM2], __uint_as_float(v & 0xFFFFFF80u));
    }
    __syncthreads();
    int node = b * 128 + t;
    if (t < 128 && node < NNODES) Dv[node] = acc[t];
}

// Fused: Yq = fp8(Z * rsqrt(clamp(Dv))), term1 partials, AND G = Y^T Y.
__global__ __launch_bounds__(256) void yzg_kernel(const float* __restrict__ Z,
                                                  const float* __restrict__ Dv,
                                                  unsigned* __restrict__ Yq32,
                                                  float* __restrict__ ZN,
                                                  float* __restrict__ G) {
    __shared__ float ys[16][KDIM];
    __shared__ float red[256];
    float acc[16];
#pragma unroll
    for (int i = 0; i < 16; ++i) acc[i] = 0.0f;
    int t = threadIdx.x;
    int c = t & 63;
    int r0 = (t >> 6) * 16;
    int row_in = t >> 4, col4 = (t & 15) * 4;
    float zn = 0.0f;
    for (int base = blockIdx.x * 16; base < NNODES; base += GMB * 16) {
        float4 v = ((const float4*)(Z + (size_t)base * KDIM))[t];
        float d = Dv[base + row_in];
        bool good = d > 0.0f;
        float r = good ? rsqrtf(d) : 1.0f;
        zn += good ? (v.x * v.x + v.y * v.y + v.z * v.z + v.w * v.w) : 0.0f;
        float y0 = v.x * r, y1 = v.y * r, y2 = v.z * r, y3 = v.w * r;
        Yq32[(size_t)(base + row_in) * 16 + (t & 15)] = pack_fp8x4(y0, y1, y2, y3);
        __syncthreads();
        ys[row_in][col4 + 0] = y0;
        ys[row_in][col4 + 1] = y1;
        ys[row_in][col4 + 2] = y2;
        ys[row_in][col4 + 3] = y3;
        __syncthreads();
#pragma unroll 4
        for (int i = 0; i < 16; ++i) {
            float yc = ys[i][c];
#pragma unroll
            for (int rr = 0; rr < 16; ++rr) acc[rr] += ys[i][r0 + rr] * yc;
        }
    }
#pragma unroll
    for (int rr = 0; rr < 16; ++rr) atomicAdd(&G[(r0 + rr) * KDIM + c], acc[rr]);
    red[t] = zn;
    __syncthreads();
    for (int s = 128; s > 0; s >>= 1) {
        if (t < s) red[t] += red[t + s];
        __syncthreads();
    }
    if (t == 0) ZN[blockIdx.x] = red[0];
}

// Per-bucket edge term: 64 local edges, 256 threads (4 waves), LDS counting
// sort, then u32 fp8 gather; 4 member slots x 16 k-quads per wave.
__global__ __launch_bounds__(256) void bedge_kernel(const unsigned* __restrict__ Yq32,
                                                    const float* __restrict__ w,
                                                    const unsigned* __restrict__ S1,
                                                    const unsigned* __restrict__ cntb,
                                                    float* __restrict__ part) {
    __shared__ unsigned lhist[64], loffs[64], lcur[64];
    __shared__ unsigned snode[CAP1];
    __shared__ float wred[4];
    int t = threadIdx.x, b = blockIdx.x;
    if (t < 64) lhist[t] = 0u;
    __syncthreads();
    unsigned cnt = cntb[b];
    const unsigned* src = S1 + (size_t)b * CAP1;
    for (unsigned i = t; i < cnt; i += 256)
        atomicAdd(&lhist[src[i] >> 17], 1u);
    __syncthreads();
    if (t < 64) {
        unsigned v = lhist[t], x = v;
#pragma unroll
        for (int off = 1; off < 64; off <<= 1) {
            unsigned y = __shfl_up(x, off);
            if (t >= off) x += y;
        }
        loffs[t] = x - v;
        lcur[t] = x - v;
    }
    __syncthreads();
    for (unsigned i = t; i < cnt; i += 256) {
        unsigned e = src[i];
        unsigned pos = atomicAdd(&lcur[e >> 17], 1u);
        snode[pos] = e & 0x1FFFFu;
    }
    __syncthreads();
    int wv = t >> 6, lane = t & 63, ms = lane >> 4, kq = lane & 15;
    float acc = 0.0f;
    for (int el = wv; el < 64; el += 4) {
        unsigned n = lhist[el];
        if (!n) continue;
        unsigned beg = loffs[el];
        float s0 = 0.0f, s1 = 0.0f, s2 = 0.0f, s3 = 0.0f;
        for (unsigned m = 0; m < n; m += 4) {
            unsigned mi = m + (unsigned)ms;
            bool ok = mi < n;
            unsigned node = snode[beg + (ok ? mi : n - 1)];
            unsigned v = Yq32[node * 16u + (unsigned)kq];
            float y0 = dec_fp8<0>(v), y1 = dec_fp8<1>(v);
            float y2 = dec_fp8<2>(v), y3 = dec_fp8<3>(v);
            if (ok) { s0 += y0; s1 += y1; s2 += y2; s3 += y3; }
        }
        s0 += __shfl_xor(s0, 16); s0 += __shfl_xor(s0, 32);
        s1 += __shfl_xor(s1, 16); s1 += __shfl_xor(s1, 32);
        s2 += __shfl_xor(s2, 16); s2 += __shfl_xor(s2, 32);
        s3 += __shfl_xor(s3, 16); s3 += __shfl_xor(s3, 32);
        float a = s0 * s0 + s1 * s1 + s2 * s2 + s3 * s3;
        a += __shfl_xor(a, 1); a += __shfl_xor(a, 2);
        a += __shfl_xor(a, 4); a += __shfl_xor(a, 8);
        if (lane == 0) acc += (w[b * 64 + el] / (float)n) * a;
    }
    if (lane == 0) wred[wv] = acc;
    __syncthreads();
    if (t == 0) part[b] = (wred[0] + wred[1]) + (wred[2] + wred[3]);
}

// Final: out = sum(ZN) - sum(part) + LAMBDA * ||G - I||_F
__global__ void final_kernel(const float* __restrict__ G,
                             const float* __restrict__ ZN,
                             const float* __restrict__ part,
                             float* __restrict__ out) {
    __shared__ float r1[256], r2[256];
    int t = threadIdx.x;
    float zn = 0.0f, pe = 0.0f, gg = 0.0f;
    if (t < GMB) zn = ZN[t];
    for (int i = t; i < NB1; i += 256) pe += part[i];
    for (int i = t; i < KDIM * KDIM; i += 256) {
        int r = i >> 6, c = i & 63;
        float g = G[i] - ((r == c) ? 1.0f : 0.0f);
        gg += g * g;
    }
    r1[t] = zn - pe; r2[t] = gg;
    __syncthreads();
    for (int s = 128; s > 0; s >>= 1) {
        if (t < s) { r1[t] += r1[t + s]; r2[t] += r2[t + s]; }
        __syncthreads();
    }
    if (t == 0) out[0] = r1[0] + LAMBDA * sqrtf(r2[0]);
}

extern "C" void kernel_launch(void* const* d_in, const int* in_sizes, int n_in,
                              void* d_out, int out_size, void* d_ws, size_t ws_size,
                              hipStream_t stream) {
    const float* Z = (const float*)d_in[0];
    const unsigned* idx = (const unsigned*)d_in[1];
    const float* w = (const float*)d_in[3];
    float* out = (float*)d_out;
    char* ws = (char*)d_ws;

    float* Dv       = (float*)(ws + OFF_DV);
    float* G        = (float*)(ws + OFF_G);
    float* part     = (float*)(ws + OFF_PART);
    float* ZN       = (float*)(ws + OFF_ZN);
    unsigned* cntb  = (unsigned*)(ws + OFF_CNTB);
    unsigned* cntb2 = (unsigned*)(ws + OFF_CNTB2);
    unsigned* hist  = (unsigned*)(ws + OFF_HIST);
    unsigned* hist2 = (unsigned*)(ws + OFF_HIST2);
    unsigned* base1 = (unsigned*)(ws + OFF_BASE1);
    unsigned* base2 = (unsigned*)(ws + OFF_BASE2);
    unsigned* S1    = (unsigned*)(ws + OFF_S1);
    unsigned* S2    = (unsigned*)(ws + OFF_S2);
    unsigned* Yq32  = (unsigned*)(ws + OFF_YQ);

    hipMemsetAsync(G, 0, KDIM * KDIM * sizeof(float), stream);
    binh_kernel<<<2 * A0B, A0T, 0, stream>>>(idx, hist, hist2);
    bscan_kernel<<<11, 256, 0, stream>>>(hist, hist2, base1, base2, cntb, cntb2);
    bscat_kernel<<<2 * A0B, A0T, 0, stream>>>(idx, w, hist, hist2, base1, base2, S1, S2);
    dvb_kernel<<<NB2, 256, 0, stream>>>(S2, cntb2, Dv);
    yzg_kernel<<<GMB, 256, 0, stream>>>(Z, Dv, Yq32, ZN, G);
    bedge_kernel<<<NB1, 256, 0, stream>>>(Yq32, w, S1, cntb, part);
    final_kernel<<<1, 256, 0, stream>>>(G, ZN, part, out);
}

// Round 9
// 135.530 us; speedup vs baseline: 1.1336x; 1.1336x over previous
//
#include <hip/hip_runtime.h>
#include <math.h>

#define NNODES 100000
#define NEDGES 100000
#define NNZV   1600000
#define KDIM   64
#define LAMBDA 0.1f

#define NB    782        // ceil(100000/128) buckets (edge>>7 / node>>7)
#define BSH   7
#define BMASK 127
#define CAP   3072       // per-bucket capacity (mean 2048, sd~45)
#define A0B   256        // chunks (CHUNK elements each)
#define A0T   1024
#define CHUNK 6250       // NNZV / A0B exactly
#define GMB   256        // blocks for fused yzg kernel

// ---- workspace layout (bytes), all offsets 256-aligned ----
#define OFF_DV      0           // N f32 (fully written by dvb)
#define OFF_G       400128      // 4096 f32 (memset, atomic accum)
#define OFF_PART    416512      // NB f32
#define OFF_ZN      419840      // GMB f32
#define OFF_CNTB    444928      // NB u32 (S1 bucket totals)
#define OFF_CNTB2   448256      // NB u32 (S2 bucket totals)
#define OFF_HIST    451584      // A0B*NB u32 counts (S1)
#define OFF_HIST2   1252352     // A0B*NB u32 counts (S2)
#define OFF_BASE1   2053120     // A0B*NB u32 absolute bases (S1)
#define OFF_BASE2   2853888     // A0B*NB u32 absolute bases (S2)
#define OFF_S1      3654656     // NB*CAP u32 (edge-bucketed: node|elocal<<17)
#define OFF_S2      13263872    // NB*CAP u32 (node-bucketed: edge|nlocal<<17)
#define OFF_YQ      22873088    // N*K fp8 = 6400000
// total 29273088

#if defined(__has_builtin)
#if __has_builtin(__builtin_amdgcn_cvt_f32_fp8)
#define HAS_CVT_FP8 1
#endif
#if __has_builtin(__builtin_amdgcn_cvt_pk_fp8_f32)
#define HAS_PK_FP8 1
#endif
#endif

__device__ __forceinline__ int load_node(const unsigned* idx, int i, bool i64) {
    return (int)(i64 ? idx[2 * i] : idx[i]);
}
__device__ __forceinline__ int load_edge(const unsigned* idx, int i, bool i64) {
    return (int)(i64 ? idx[2 * (NNZV + i)] : idx[NNZV + i]);
}

// f32 -> fp8 e4m3fn, RNE (fallback when no HW packed cvt).
__device__ __forceinline__ unsigned char enc_fp8(float x) {
    unsigned u = __float_as_uint(x);
    unsigned s = (u >> 31) << 7;
    unsigned mag = u & 0x7FFFFFFFu;
    if (mag >= 0x43E00000u) return (unsigned char)(s | 0x7Eu);
    if (mag < 0x3C800000u) {
        float a = __uint_as_float(mag);
        int m = (int)rintf(a * 512.0f);
        if (m >= 8) return (unsigned char)(s | 0x08u);
        return (unsigned char)(s | (unsigned)m);
    }
    unsigned lsb = (mag >> 20) & 1u;
    mag += 0x0007FFFFu + lsb;
    unsigned e = (mag >> 23) - 120u;
    return (unsigned char)(s | (e << 3) | ((mag >> 20) & 7u));
}

// Pack 4 f32 -> 4 fp8 bytes (HW packed converter when available).
__device__ __forceinline__ unsigned pack_fp8x4(float y0, float y1, float y2, float y3) {
#ifdef HAS_PK_FP8
    int q = 0;
    q = __builtin_amdgcn_cvt_pk_fp8_f32(y0, y1, q, false);
    q = __builtin_amdgcn_cvt_pk_fp8_f32(y2, y3, q, true);
    return (unsigned)q;
#else
    return (unsigned)enc_fp8(y0) | ((unsigned)enc_fp8(y1) << 8) |
           ((unsigned)enc_fp8(y2) << 16) | ((unsigned)enc_fp8(y3) << 24);
#endif
}

// fp8 e4m3fn byte SEL of v -> f32.
template <int SEL>
__device__ __forceinline__ float dec_fp8(unsigned v) {
#ifdef HAS_CVT_FP8
    return __builtin_amdgcn_cvt_f32_fp8(v, SEL);
#else
    unsigned b = (v >> (8 * SEL)) & 0xFFu;
    unsigned e = (b >> 3) & 15u, m = b & 7u;
    float f = e ? __uint_as_float(((e + 120u) << 23) | (m << 20))
                : (float)m * 0.001953125f;
    return (b & 128u) ? -f : f;
#endif
}

// A0: histogram. Grid 2*A0B: which = blockIdx>>8 (0: edge keys, 1: node keys).
__global__ __launch_bounds__(A0T) void binh_kernel(const unsigned* __restrict__ idx,
                                                   unsigned* __restrict__ hist,
                                                   unsigned* __restrict__ hist2) {
    __shared__ unsigned h[NB];
    __shared__ unsigned fred[16];
    int which = blockIdx.x >> 8, chunk = blockIdx.x & (A0B - 1);
    int t = threadIdx.x, wave = t >> 6, lane = t & 63;
    unsigned hv = idx[2 * t + 1];            // high word if i64; random idx if i32
#pragma unroll
    for (int off = 32; off; off >>= 1) hv |= __shfl_xor(hv, off);
    if (lane == 0) fred[wave] = hv;
    for (int j = t; j < NB; j += A0T) h[j] = 0u;
    __syncthreads();
    unsigned o = 0;
#pragma unroll
    for (int k = 0; k < 16; ++k) o |= fred[k];
    bool i64 = (o == 0u);
    int base = chunk * CHUNK;
    if (which == 0) {
        for (int i = base + t; i < base + CHUNK; i += A0T)
            atomicAdd(&h[load_edge(idx, i, i64) >> BSH], 1u);
    } else {
        for (int i = base + t; i < base + CHUNK; i += A0T)
            atomicAdd(&h[load_node(idx, i, i64) >> BSH], 1u);
    }
    __syncthreads();
    unsigned* H = which ? hist2 : hist;
    for (int j = t; j < NB; j += A0T) H[chunk * NB + j] = h[j];
}

// A1: per-bucket column scan -> absolute per-(chunk,bucket) bases; totals.
__global__ void bscan_kernel(const unsigned* __restrict__ hist,
                             const unsigned* __restrict__ hist2,
                             unsigned* __restrict__ base1,
                             unsigned* __restrict__ base2,
                             unsigned* __restrict__ cntb,
                             unsigned* __restrict__ cntb2) {
    int which = blockIdx.x >> 2;
    int b = (blockIdx.x & 3) * 256 + threadIdx.x;
    if (b >= NB) return;
    const unsigned* h = which ? hist2 : hist;
    unsigned* ba = which ? base2 : base1;
    unsigned run = 0;
    for (int blk = 0; blk < A0B; ++blk) {
        unsigned v = h[blk * NB + b];
        ba[blk * NB + b] = (unsigned)b * CAP + run;
        run += v;
    }
    (which ? cntb2 : cntb)[b] = run;
}

// A2: LDS-staged multisplit scatter. Grid 2*A0B: which selects S1/S2.
// Copy-out: 8 buckets per wave, 8 lanes each.
__global__ __launch_bounds__(A0T) void bscat_kernel(const unsigned* __restrict__ idx,
                                                    const unsigned* __restrict__ hist,
                                                    const unsigned* __restrict__ hist2,
                                                    const unsigned* __restrict__ base1,
                                                    const unsigned* __restrict__ base2,
                                                    unsigned* __restrict__ S1,
                                                    unsigned* __restrict__ S2) {
    __shared__ unsigned stage[CHUNK];
    __shared__ unsigned cur[NB];
    __shared__ unsigned wsum[16], fred[16];
    int which = blockIdx.x >> 8, chunk = blockIdx.x & (A0B - 1);
    int t = threadIdx.x, wave = t >> 6, lane = t & 63;

    unsigned hv = idx[2 * t + 1];
#pragma unroll
    for (int off = 32; off; off >>= 1) hv |= __shfl_xor(hv, off);
    if (lane == 0) fred[wave] = hv;

    const unsigned* H = which ? hist2 : hist;
    const unsigned* B = which ? base2 : base1;
    unsigned* S = which ? S2 : S1;

    unsigned v = (t < NB) ? H[chunk * NB + t] : 0u;
    unsigned x = v;
#pragma unroll
    for (int off = 1; off < 64; off <<= 1) {
        unsigned y = __shfl_up(x, off);
        if (lane >= off) x += y;
    }
    if (lane == 63) wsum[wave] = x;
    __syncthreads();
    if (t < 16) {
        unsigned a = wsum[t], y = a;
#pragma unroll
        for (int off = 1; off < 16; off <<= 1) {
            unsigned z = __shfl_up(y, off);
            if (t >= off) y += z;
        }
        wsum[t] = y - a;
    }
    __syncthreads();
    if (t < NB) cur[t] = wsum[wave] + x - v;
    unsigned o = 0;
#pragma unroll
    for (int k = 0; k < 16; ++k) o |= fred[k];
    bool i64 = (o == 0u);
    __syncthreads();

    int base = chunk * CHUNK;
    for (int i = base + t; i < base + CHUNK; i += A0T) {
        int node = load_node(idx, i, i64);
        int edge = load_edge(idx, i, i64);
        unsigned key, val;
        if (which == 0) {
            key = (unsigned)edge >> BSH;
            val = (unsigned)node | ((unsigned)(edge & BMASK) << 17);
        } else {
            key = (unsigned)node >> BSH;
            val = (unsigned)edge | ((unsigned)(node & BMASK) << 17);
        }
        unsigned p = atomicAdd(&cur[key], 1u);
        stage[p] = val;
    }
    __syncthreads();

    int li = lane & 7;
    for (int bb = wave * 8 + (lane >> 3); bb < NB; bb += 128) {
        unsigned c = H[chunk * NB + bb];
        unsigned st = cur[bb] - c;
        unsigned g = B[chunk * NB + bb];
        for (unsigned m = li; m < c; m += 8) S[g + m] = stage[st + m];
    }
}

// Dv build: per node-bucket LDS f32 accumulation (w gathered from L2).
__global__ __launch_bounds__(256) void dvb_kernel(const unsigned* __restrict__ S2,
                                                  const unsigned* __restrict__ cntb2,
                                                  const float* __restrict__ w,
                                                  float* __restrict__ Dv) {
    __shared__ float acc[128];
    int t = threadIdx.x, b = blockIdx.x;
    if (t < 128) acc[t] = 0.0f;
    __syncthreads();
    unsigned cnt = cntb2[b];
    const unsigned* src = S2 + (size_t)b * CAP;
    for (unsigned i = t; i < cnt; i += 256) {
        unsigned e = src[i];
        atomicAdd(&acc[e >> 17], w[e & 0x1FFFFu]);
    }
    __syncthreads();
    int node = b * 128 + t;
    if (t < 128 && node < NNODES) Dv[node] = acc[t];
}

// Fused: Yq = fp8(Z * rsqrt(clamp(Dv))), term1 partials, AND G = Y^T Y.
__global__ __launch_bounds__(256) void yzg_kernel(const float* __restrict__ Z,
                                                  const float* __restrict__ Dv,
                                                  unsigned* __restrict__ Yq32,
                                                  float* __restrict__ ZN,
                                                  float* __restrict__ G) {
    __shared__ float ys[16][KDIM];
    __shared__ float red[256];
    float acc[16];
#pragma unroll
    for (int i = 0; i < 16; ++i) acc[i] = 0.0f;
    int t = threadIdx.x;
    int c = t & 63;
    int r0 = (t >> 6) * 16;
    int row_in = t >> 4, col4 = (t & 15) * 4;
    float zn = 0.0f;
    for (int base = blockIdx.x * 16; base < NNODES; base += GMB * 16) {
        float4 v = ((const float4*)(Z + (size_t)base * KDIM))[t];
        float d = Dv[base + row_in];
        bool good = d > 0.0f;
        float r = good ? rsqrtf(d) : 1.0f;
        zn += good ? (v.x * v.x + v.y * v.y + v.z * v.z + v.w * v.w) : 0.0f;
        float y0 = v.x * r, y1 = v.y * r, y2 = v.z * r, y3 = v.w * r;
        Yq32[(size_t)(base + row_in) * 16 + (t & 15)] = pack_fp8x4(y0, y1, y2, y3);
        __syncthreads();                      // protect ys from previous iteration
        ys[row_in][col4 + 0] = y0;
        ys[row_in][col4 + 1] = y1;
        ys[row_in][col4 + 2] = y2;
        ys[row_in][col4 + 3] = y3;
        __syncthreads();
#pragma unroll 4
        for (int i = 0; i < 16; ++i) {
            float yc = ys[i][c];
#pragma unroll
            for (int rr = 0; rr < 16; ++rr) acc[rr] += ys[i][r0 + rr] * yc;
        }
    }
#pragma unroll
    for (int rr = 0; rr < 16; ++rr) atomicAdd(&G[(r0 + rr) * KDIM + c], acc[rr]);
    red[t] = zn;
    __syncthreads();
    for (int s = 128; s > 0; s >>= 1) {
        if (t < s) red[t] += red[t + s];
        __syncthreads();
    }
    if (t == 0) ZN[blockIdx.x] = red[0];
}

// Per-bucket edge term: LDS counting sort over 128 local edges, then
// u32 fp8 gather with x4 member unroll: 16 independent loads in flight
// per wave (4 slots x 4 unroll) before any decode.
__global__ __launch_bounds__(512) void bedge_kernel(const unsigned* __restrict__ Yq32,
                                                    const float* __restrict__ w,
                                                    const unsigned* __restrict__ S1,
                                                    const unsigned* __restrict__ cntb,
                                                    float* __restrict__ part) {
    __shared__ unsigned lhist[128], loffs[128], lcur[128];
    __shared__ unsigned snode[CAP];
    __shared__ float wred[8];
    int t = threadIdx.x, b = blockIdx.x;
    if (t < 128) lhist[t] = 0u;
    __syncthreads();
    unsigned cnt = cntb[b];
    const unsigned* src = S1 + (size_t)b * CAP;
    for (unsigned i = t; i < cnt; i += 512)
        atomicAdd(&lhist[src[i] >> 17], 1u);
    __syncthreads();
    if (t < 64) {
        unsigned a = lhist[2 * t], bb = lhist[2 * t + 1];
        unsigned sp = a + bb, x = sp;
#pragma unroll
        for (int off = 1; off < 64; off <<= 1) {
            unsigned y = __shfl_up(x, off);
            if (t >= off) x += y;
        }
        unsigned ex = x - sp;
        loffs[2 * t] = ex;          lcur[2 * t] = ex;
        loffs[2 * t + 1] = ex + a;  lcur[2 * t + 1] = ex + a;
    }
    __syncthreads();
    for (unsigned i = t; i < cnt; i += 512) {
        unsigned e = src[i];
        unsigned pos = atomicAdd(&lcur[e >> 17], 1u);
        snode[pos] = e & 0x1FFFFu;
    }
    __syncthreads();
    int wv = t >> 6, lane = t & 63, ms = lane >> 4, kq = lane & 15;
    float acc = 0.0f;
    for (int el = wv; el < 128; el += 8) {
        unsigned n = lhist[el];
        if (!n) continue;
        unsigned beg = loffs[el];
        float s0 = 0.0f, s1 = 0.0f, s2 = 0.0f, s3 = 0.0f;
        for (unsigned m = 0; m < n; m += 16) {
            unsigned mi0 = m + (unsigned)ms;
            unsigned mi1 = mi0 + 4, mi2 = mi0 + 8, mi3 = mi0 + 12;
            bool ok0 = mi0 < n, ok1 = mi1 < n, ok2 = mi2 < n, ok3 = mi3 < n;
            unsigned nd0 = snode[beg + (ok0 ? mi0 : 0)];
            unsigned nd1 = snode[beg + (ok1 ? mi1 : 0)];
            unsigned nd2 = snode[beg + (ok2 ? mi2 : 0)];
            unsigned nd3 = snode[beg + (ok3 ? mi3 : 0)];
            // 4 independent gathers issued back-to-back (MLP)
            unsigned v0 = Yq32[nd0 * 16u + (unsigned)kq];
            unsigned v1 = Yq32[nd1 * 16u + (unsigned)kq];
            unsigned v2 = Yq32[nd2 * 16u + (unsigned)kq];
            unsigned v3 = Yq32[nd3 * 16u + (unsigned)kq];
            if (ok0) { s0 += dec_fp8<0>(v0); s1 += dec_fp8<1>(v0);
                       s2 += dec_fp8<2>(v0); s3 += dec_fp8<3>(v0); }
            if (ok1) { s0 += dec_fp8<0>(v1); s1 += dec_fp8<1>(v1);
                       s2 += dec_fp8<2>(v1); s3 += dec_fp8<3>(v1); }
            if (ok2) { s0 += dec_fp8<0>(v2); s1 += dec_fp8<1>(v2);
                       s2 += dec_fp8<2>(v2); s3 += dec_fp8<3>(v2); }
            if (ok3) { s0 += dec_fp8<0>(v3); s1 += dec_fp8<1>(v3);
                       s2 += dec_fp8<2>(v3); s3 += dec_fp8<3>(v3); }
        }
        s0 += __shfl_xor(s0, 16); s0 += __shfl_xor(s0, 32);
        s1 += __shfl_xor(s1, 16); s1 += __shfl_xor(s1, 32);
        s2 += __shfl_xor(s2, 16); s2 += __shfl_xor(s2, 32);
        s3 += __shfl_xor(s3, 16); s3 += __shfl_xor(s3, 32);
        float a = s0 * s0 + s1 * s1 + s2 * s2 + s3 * s3;
        a += __shfl_xor(a, 1); a += __shfl_xor(a, 2);
        a += __shfl_xor(a, 4); a += __shfl_xor(a, 8);
        if (lane == 0) acc += (w[b * 128 + el] / (float)n) * a;
    }
    if (lane == 0) wred[wv] = acc;
    __syncthreads();
    if (t == 0) {
        float s = 0.0f;
        for (int i = 0; i < 8; ++i) s += wred[i];
        part[b] = s;
    }
}

// Final: out = sum(ZN) - sum(part) + LAMBDA * ||G - I||_F
__global__ void final_kernel(const float* __restrict__ G,
                             const float* __restrict__ ZN,
                             const float* __restrict__ part,
                             float* __restrict__ out) {
    __shared__ float r1[256], r2[256];
    int t = threadIdx.x;
    float zn = 0.0f, pe = 0.0f, gg = 0.0f;
    if (t < GMB) zn = ZN[t];
    for (int i = t; i < NB; i += 256) pe += part[i];
    for (int i = t; i < KDIM * KDIM; i += 256) {
        int r = i >> 6, c = i & 63;
        float g = G[i] - ((r == c) ? 1.0f : 0.0f);
        gg += g * g;
    }
    r1[t] = zn - pe; r2[t] = gg;
    __syncthreads();
    for (int s = 128; s > 0; s >>= 1) {
        if (t < s) { r1[t] += r1[t + s]; r2[t] += r2[t + s]; }
        __syncthreads();
    }
    if (t == 0) out[0] = r1[0] + LAMBDA * sqrtf(r2[0]);
}

extern "C" void kernel_launch(void* const* d_in, const int* in_sizes, int n_in,
                              void* d_out, int out_size, void* d_ws, size_t ws_size,
                              hipStream_t stream) {
    const float* Z = (const float*)d_in[0];
    const unsigned* idx = (const unsigned*)d_in[1];
    const float* w = (const float*)d_in[3];
    float* out = (float*)d_out;
    char* ws = (char*)d_ws;

    float* Dv       = (float*)(ws + OFF_DV);
    float* G        = (float*)(ws + OFF_G);
    float* part     = (float*)(ws + OFF_PART);
    float* ZN       = (float*)(ws + OFF_ZN);
    unsigned* cntb  = (unsigned*)(ws + OFF_CNTB);
    unsigned* cntb2 = (unsigned*)(ws + OFF_CNTB2);
    unsigned* hist  = (unsigned*)(ws + OFF_HIST);
    unsigned* hist2 = (unsigned*)(ws + OFF_HIST2);
    unsigned* base1 = (unsigned*)(ws + OFF_BASE1);
    unsigned* base2 = (unsigned*)(ws + OFF_BASE2);
    unsigned* S1    = (unsigned*)(ws + OFF_S1);
    unsigned* S2    = (unsigned*)(ws + OFF_S2);
    unsigned* Yq32  = (unsigned*)(ws + OFF_YQ);

    hipMemsetAsync(G, 0, KDIM * KDIM * sizeof(float), stream);
    binh_kernel<<<2 * A0B, A0T, 0, stream>>>(idx, hist, hist2);
    bscan_kernel<<<8, 256, 0, stream>>>(hist, hist2, base1, base2, cntb, cntb2);
    bscat_kernel<<<2 * A0B, A0T, 0, stream>>>(idx, hist, hist2, base1, base2, S1, S2);
    dvb_kernel<<<NB, 256, 0, stream>>>(S2, cntb2, w, Dv);
    yzg_kernel<<<GMB, 256, 0, stream>>>(Z, Dv, Yq32, ZN, G);
    bedge_kernel<<<NB, 512, 0, stream>>>(Yq32, w, S1, cntb, part);
    final_kernel<<<1, 256, 0, stream>>>(G, ZN, part, out);
}